// Round 5
// baseline (11000.621 us; speedup 1.0000x reference)
//
#include <hip/hip_runtime.h>
#include <hip/hip_bf16.h>

typedef unsigned short ushort_t;
typedef unsigned int uint32;
typedef unsigned long long ull;
typedef short bf16x8 __attribute__((ext_vector_type(8)));
typedef float f32x4 __attribute__((ext_vector_type(4)));

#define Bb 64
#define Tt 512
#define Dd 512
#define Hh 1024
#define KK 1536
#define NBLK 64
#define OUT2_OFF 33554432ull
#define FLAGS_OFF 9699328ull
#define XB_OFF    9707776ull
#define XB_BYTES  33554432ull

// ws: HB @0 (128K) | RH @131072 (128K) | WT @262144 (9.4M) | flags @9699328 | XB @9707776 (32M opt)

__device__ inline ushort_t f2b(float f) {
    __hip_bfloat16 h = __float2bfloat16(f);
    return __builtin_bit_cast(ushort_t, h);
}
__device__ inline float b2f(ushort_t u) {
    uint32 x = ((uint32)u) << 16;
    return __builtin_bit_cast(float, x);
}
__device__ inline bf16x8 ld_bf8(const ushort_t* p) {
    uint4 v = *reinterpret_cast<const uint4*>(p);
    return __builtin_bit_cast(bf16x8, v);
}
__device__ inline bf16x8 ld_x8(const float* p) {
    float4 u = *reinterpret_cast<const float4*>(p);
    float4 v = *reinterpret_cast<const float4*>(p + 4);
    bf16x8 a;
    a[0] = (short)f2b(u.x); a[1] = (short)f2b(u.y); a[2] = (short)f2b(u.z); a[3] = (short)f2b(u.w);
    a[4] = (short)f2b(v.x); a[5] = (short)f2b(v.y); a[6] = (short)f2b(v.z); a[7] = (short)f2b(v.w);
    return a;
}
// device-coherent (LLC) 16B load: 2 relaxed agent atomics — bypass L1/L2, no cache maintenance
__device__ inline bf16x8 ld_a8(const ushort_t* p) {
    union { ull q[2]; bf16x8 v; } u;
    u.q[0] = __hip_atomic_load((const ull*)p,       __ATOMIC_RELAXED, __HIP_MEMORY_SCOPE_AGENT);
    u.q[1] = __hip_atomic_load((const ull*)(p + 4), __ATOMIC_RELAXED, __HIP_MEMORY_SCOPE_AGENT);
    return u.v;
}
__device__ inline void st_a8(ushort_t* p, ull v) {
    __hip_atomic_store((ull*)p, v, __ATOMIC_RELAXED, __HIP_MEMORY_SCOPE_AGENT);
}

#define MFMA(a, b, c) __builtin_amdgcn_mfma_f32_16x16x32_bf16((a), (b), (c), 0, 0, 0)

__device__ inline void b_arrive(uint32* flags, uint32 val) {
    asm volatile("s_waitcnt vmcnt(0)" ::: "memory");
    __syncthreads();
    if (threadIdx.x == 0)
        __hip_atomic_store(flags + (uint32)blockIdx.x * 32, val,
                           __ATOMIC_RELAXED, __HIP_MEMORY_SCOPE_AGENT);
}
__device__ inline void b_wait(uint32* flags, uint32 val) {
    if (threadIdx.x < 64) {
        uint32 v;
        do {
            v = __hip_atomic_load(flags + threadIdx.x * 32,
                                  __ATOMIC_RELAXED, __HIP_MEMORY_SCOPE_AGENT);
        } while (__any((int)(v < val)));
    }
    __syncthreads();
    asm volatile("" ::: "memory");
}

// cross-wave K-partial reduction through 12KB LDS (wave m finalizes m-tile m).
// slots: writer w for tile m -> m*3 + (w<m ? w : w-1); reader (wave w) reads w*3+0..2.
#define REDUCE(acc, tot)                                                          \
    {                                                                             \
        __syncthreads();                                                          \
        _Pragma("unroll")                                                         \
        for (int m_ = 0; m_ < 4; m_++) {                                          \
            if (m_ != w) {                                                        \
                int s_ = m_ * 3 + (w < m_ ? w : w - 1);                           \
                *reinterpret_cast<f32x4*>(&RED[s_ * 256 + l * 4]) = acc[m_];      \
            }                                                                     \
        }                                                                         \
        __syncthreads();                                                          \
        tot = (w == 0) ? acc[0] : (w == 1) ? acc[1] : (w == 2) ? acc[2] : acc[3]; \
        _Pragma("unroll")                                                         \
        for (int i_ = 0; i_ < 3; i_++)                                            \
            tot += *reinterpret_cast<f32x4*>(&RED[(w * 3 + i_) * 256 + l * 4]);   \
    }

__global__ __launch_bounds__(256) void k_init(const float* __restrict__ state,
                                              ushort_t* __restrict__ HB, uint32* flags) {
    int i = blockIdx.x * 256 + threadIdx.x;
    if (i < Bb * Hh) HB[i] = f2b(state[i]);
    if (i < 2112) flags[i] = 0;
}

__global__ __launch_bounds__(256) void k_xb(const float* __restrict__ inp,
                                            ushort_t* __restrict__ XB) {
    size_t i = ((size_t)blockIdx.x * 256 + threadIdx.x) * 8;
    bf16x8 v = ld_x8(inp + i);
    *reinterpret_cast<uint4*>(XB + i) = __builtin_bit_cast(uint4, v);
}

// WT[g][n][k] = bf16( k<512 ? Wx_g[k][n] : Wh_g[k-512][n] )
__global__ __launch_bounds__(256) void k_wt(const float* __restrict__ Wxz, const float* __restrict__ Whz,
                                            const float* __restrict__ Wxr, const float* __restrict__ Whr,
                                            const float* __restrict__ Wxh, const float* __restrict__ Whh,
                                            ushort_t* __restrict__ WT) {
    __shared__ float lds[64][65];
    int id = blockIdx.x;
    int g = id / 384, rem = id % 384, nt = rem / 24, kt = rem % 24;
    const float* Wx = (g == 0) ? Wxz : (g == 1) ? Wxr : Wxh;
    const float* Wh = (g == 0) ? Whz : (g == 1) ? Whr : Whh;
    int n0 = nt * 64, k0 = kt * 64;
    int tr = threadIdx.x >> 6, tc = threadIdx.x & 63;
    #pragma unroll
    for (int i = 0; i < 16; i++) {
        int kl = i * 4 + tr, k = k0 + kl;
        lds[kl][tc] = (k < 512) ? Wx[(size_t)k * Hh + n0 + tc]
                                : Wh[(size_t)(k - 512) * Hh + n0 + tc];
    }
    __syncthreads();
    #pragma unroll
    for (int i = 0; i < 16; i++) {
        int nl = i * 4 + tr;
        WT[((size_t)g * Hh + n0 + nl) * KK + k0 + tc] = f2b(lds[tc][nl]);
    }
}

__global__ __launch_bounds__(256, 1) void gru_persist(
    const float* __restrict__ inp, const ushort_t* __restrict__ XB, int use_xb,
    const float* __restrict__ bz, const float* __restrict__ br, const float* __restrict__ bh,
    ushort_t* HB, ushort_t* RH, const ushort_t* __restrict__ WT,
    uint32* flags, float* __restrict__ out) {
    // WL: per gate 48 tiles of [16 col][32 k] bf16 (1KB), slot-XOR-swizzled.
    __shared__ ushort_t WL[3 * 48 * 512];   // 147456 B
    __shared__ float    RED[12 * 256];      // 12288 B
    __shared__ ushort_t STG[4 * 256];       // 2048 B      total 161792 <= 160KiB

    const int bi = blockIdx.x;
    const int tid = threadIdx.x;

    // ---- prologue: stage weights into swizzled LDS tiles ----
    for (int idx = tid; idx < 9216; idx += 256) {     // 3g x 16col x 192 16B-chunks
        int g = idx / 3072, r = idx % 3072, col = r / 192, c8 = r % 192;
        int kc = c8 >> 2, slot = c8 & 3, ps = slot ^ ((col >> 1) & 3);
        const ushort_t* src = WT + ((size_t)g * Hh + bi * 16 + col) * KK + c8 * 8;
        ushort_t* dst = WL + g * 24576 + kc * 512 + col * 32 + ps * 8;
        *reinterpret_cast<uint4*>(dst) = *reinterpret_cast<const uint4*>(src);
    }

    const int l = tid & 63, w = tid >> 6;
    const int lrow = l & 15, lq = l >> 4;
    const int ncol = bi * 16 + lrow;
    const int wloff = lrow * 32 + (lq ^ ((lrow >> 1) & 3)) * 8;   // swizzled per-lane tile offset
    const float bzv = bz[ncol], brv = br[ncol], bhv = bh[ncol];

    #define WTILE(g, kc) ld_bf8(WL + (g) * 24576 + (kc) * 512 + wloff)

    // per-m A-operand bases (wave w owns k-quarter: x [w*128,+128), h [w*256,+256))
    const float*    xF[4]; const ushort_t* xB[4];
    const ushort_t* hb[4]; const ushort_t* rh[4];
    #pragma unroll
    for (int m = 0; m < 4; m++) {
        int row = m * 16 + lrow;
        xF[m] = inp + (size_t)row * (Tt * Dd) + w * 128 + lq * 8;
        xB[m] = XB  + (size_t)row * (Tt * Dd) + w * 128 + lq * 8;
        hb[m] = HB  + row * Hh + w * 256 + lq * 8;
        rh[m] = RH  + row * Hh + w * 256 + lq * 8;
    }
    // store path: wave w owns m-tile w (batch rows w*16..+16)
    const size_t strow  = (size_t)(w * 16 + (l >> 2)) * Hh + bi * 16 + (l & 3) * 4;
    const int    stg_wr = w * 256;                     // + (lq*4+j)*16 + lrow
    const int    stg_rd = w * 256 + (l >> 2) * 16 + (l & 3) * 4;

    float hold[4];
    #pragma unroll
    for (int j = 0; j < 4; j++)
        hold[j] = b2f(HB[(size_t)(w * 16 + lq * 4 + j) * Hh + ncol]);

    __syncthreads();

    for (int t = 0; t < Tt; ++t) {
        const f32x4 z4 = {0.f, 0.f, 0.f, 0.f};
        f32x4 az[4] = {z4, z4, z4, z4}, ar[4] = {z4, z4, z4, z4}, ahx[4] = {z4, z4, z4, z4};

        // ---- x-part of z, r, h (independent of HB -> overlaps barrier 2t propagation) ----
        if (use_xb) {
            #pragma unroll
            for (int kk = 0; kk < 4; kk++) {
                bf16x8 Bz = WTILE(0, w * 4 + kk);
                bf16x8 Br = WTILE(1, w * 4 + kk);
                bf16x8 Bh = WTILE(2, w * 4 + kk);
                #pragma unroll
                for (int m = 0; m < 4; m++) {
                    bf16x8 A = ld_bf8(xB[m] + (size_t)t * Dd + kk * 32);
                    az[m]  = MFMA(A, Bz, az[m]);
                    ar[m]  = MFMA(A, Br, ar[m]);
                    ahx[m] = MFMA(A, Bh, ahx[m]);
                }
            }
        } else {
            #pragma unroll
            for (int kk = 0; kk < 4; kk++) {
                bf16x8 Bz = WTILE(0, w * 4 + kk);
                bf16x8 Br = WTILE(1, w * 4 + kk);
                bf16x8 Bh = WTILE(2, w * 4 + kk);
                #pragma unroll
                for (int m = 0; m < 4; m++) {
                    bf16x8 A = ld_x8(xF[m] + (size_t)t * Dd + kk * 32);
                    az[m]  = MFMA(A, Bz, az[m]);
                    ar[m]  = MFMA(A, Br, ar[m]);
                    ahx[m] = MFMA(A, Bh, ahx[m]);
                }
            }
        }

        b_wait(flags, 2u * (uint32)t);          // HB(t) visible

        // ---- h-part of z, r: K-quarter of HB for all 4 m-tiles ----
        #pragma unroll
        for (int kk = 0; kk < 8; kk++) {
            bf16x8 Bz = WTILE(0, 16 + w * 8 + kk);
            bf16x8 Br = WTILE(1, 16 + w * 8 + kk);
            #pragma unroll
            for (int m = 0; m < 4; m++) {
                bf16x8 A = ld_a8(hb[m] + kk * 32);
                az[m] = MFMA(A, Bz, az[m]);
                ar[m] = MFMA(A, Br, ar[m]);
            }
        }

        f32x4 tz, tr;
        REDUCE(az, tz);
        REDUCE(ar, tr);

        float zreg[4];
        #pragma unroll
        for (int j = 0; j < 4; j++) {
            float zz = 1.f / (1.f + __expf(-(tz[j] + bzv)));
            float rr = 1.f / (1.f + __expf(-(tr[j] + brv)));
            zreg[j] = zz;
            STG[stg_wr + (lq * 4 + j) * 16 + lrow] = f2b(rr * hold[j]);
        }
        asm volatile("s_waitcnt lgkmcnt(0)" ::: "memory");
        st_a8(RH + strow, *reinterpret_cast<const ull*>(&STG[stg_rd]));

        f32x4 thx;
        REDUCE(ahx, thx);                        // overlaps RH store drain

        b_arrive(flags, 2u * (uint32)t + 1u);
        b_wait(flags, 2u * (uint32)t + 1u);      // RH visible

        // ---- phase B: (R*H)@W_hh, K-quarter for all 4 m-tiles ----
        f32x4 ah[4] = {z4, z4, z4, z4};
        #pragma unroll
        for (int kk = 0; kk < 8; kk++) {
            bf16x8 Bh = WTILE(2, 16 + w * 8 + kk);
            #pragma unroll
            for (int m = 0; m < 4; m++) {
                bf16x8 A = ld_a8(rh[m] + kk * 32);
                ah[m] = MFMA(A, Bh, ah[m]);
            }
        }
        f32x4 th4;
        REDUCE(ah, th4);
        th4 += thx;

        float hn[4];
        #pragma unroll
        for (int j = 0; j < 4; j++) {
            float pre = th4[j] + bhv;
            float e = __expf(-2.f * fabsf(pre));
            float v = (1.f - e) / (1.f + e);
            v = copysignf(v, pre);
            v = zreg[j] * hold[j] + (1.f - zreg[j]) * v;
            hold[j] = v;
            hn[j] = v;
            STG[stg_wr + (lq * 4 + j) * 16 + lrow] = f2b(v);
        }
        asm volatile("s_waitcnt lgkmcnt(0)" ::: "memory");
        st_a8(HB + strow, *reinterpret_cast<const ull*>(&STG[stg_rd]));
        *reinterpret_cast<float4*>(out + (size_t)ncol * (Tt * Bb) + (size_t)t * Bb + w * 16 + lq * 4) =
            make_float4(hn[0], hn[1], hn[2], hn[3]);
        if (t == Tt - 1) {
            #pragma unroll
            for (int j = 0; j < 4; j++)
                out[OUT2_OFF + (size_t)(w * 16 + lq * 4 + j) * Hh + ncol] = hn[j];
        }
        b_arrive(flags, 2u * (uint32)t + 2u);
    }
    #undef WTILE
}

extern "C" void kernel_launch(void* const* d_in, const int* in_sizes, int n_in,
                              void* d_out, int out_size, void* d_ws, size_t ws_size,
                              hipStream_t stream) {
    const float* inp   = (const float*)d_in[0];
    const float* state = (const float*)d_in[1];
    const float* Wxz   = (const float*)d_in[2];
    const float* Whz   = (const float*)d_in[3];
    const float* bz    = (const float*)d_in[4];
    const float* Wxr   = (const float*)d_in[5];
    const float* Whr   = (const float*)d_in[6];
    const float* br    = (const float*)d_in[7];
    const float* Wxh   = (const float*)d_in[8];
    const float* Whh   = (const float*)d_in[9];
    const float* bh    = (const float*)d_in[10];
    float* out = (float*)d_out;

    char* ws = (char*)d_ws;
    ushort_t* HB    = (ushort_t*)(ws);
    ushort_t* RH    = (ushort_t*)(ws + 131072);
    ushort_t* WT    = (ushort_t*)(ws + 262144);
    uint32*   flags = (uint32*)(ws + FLAGS_OFF);
    ushort_t* XB    = (ushort_t*)(ws + XB_OFF);
    int use_xb = (ws_size >= XB_OFF + XB_BYTES) ? 1 : 0;

    k_init<<<dim3(256), dim3(256), 0, stream>>>(state, HB, flags);
    k_wt<<<dim3(1152), dim3(256), 0, stream>>>(Wxz, Whz, Wxr, Whr, Wxh, Whh, WT);
    if (use_xb)
        k_xb<<<dim3(8192), dim3(256), 0, stream>>>(inp, XB);

    void* args[] = {(void*)&inp, (void*)&XB, (void*)&use_xb,
                    (void*)&bz, (void*)&br, (void*)&bh,
                    (void*)&HB, (void*)&RH, (void*)&WT, (void*)&flags, (void*)&out};
    hipError_t e = hipLaunchCooperativeKernel((const void*)gru_persist, dim3(NBLK), dim3(256),
                                              args, 0, stream);
    if (e != hipSuccess) {
        gru_persist<<<dim3(NBLK), dim3(256), 0, stream>>>(inp, XB, use_xb, bz, br, bh,
                                                          HB, RH, WT, flags, out);
    }
}

// Round 6
// 9906.171 us; speedup vs baseline: 1.1105x; 1.1105x over previous
//
#include <hip/hip_runtime.h>
#include <hip/hip_bf16.h>

typedef unsigned short ushort_t;
typedef unsigned int uint32;
typedef unsigned long long ull;
typedef short bf16x8 __attribute__((ext_vector_type(8)));
typedef float f32x4 __attribute__((ext_vector_type(4)));

#define Bb 64
#define Tt 512
#define Dd 512
#define Hh 1024
#define KK 1536
#define NBLK 64
#define OUT2_OFF 33554432ull
#define FLAGS_OFF 9699328ull
#define XB_OFF    9707776ull
#define XB_BYTES  33554432ull

// ws: HB @0 (128K) | RH @131072 (128K) | WT @262144 (9.4M) | flags @9699328 | XB @9707776 (32M opt)

__device__ inline ushort_t f2b(float f) {
    __hip_bfloat16 h = __float2bfloat16(f);
    return __builtin_bit_cast(ushort_t, h);
}
__device__ inline float b2f(ushort_t u) {
    uint32 x = ((uint32)u) << 16;
    return __builtin_bit_cast(float, x);
}
__device__ inline bf16x8 ld_bf8(const ushort_t* p) {
    uint4 v = *reinterpret_cast<const uint4*>(p);
    return __builtin_bit_cast(bf16x8, v);
}
__device__ inline bf16x8 ld_x8(const float* p) {
    float4 u = *reinterpret_cast<const float4*>(p);
    float4 v = *reinterpret_cast<const float4*>(p + 4);
    bf16x8 a;
    a[0] = (short)f2b(u.x); a[1] = (short)f2b(u.y); a[2] = (short)f2b(u.z); a[3] = (short)f2b(u.w);
    a[4] = (short)f2b(v.x); a[5] = (short)f2b(v.y); a[6] = (short)f2b(v.z); a[7] = (short)f2b(v.w);
    return a;
}
// L1/L2-bypassing (LLC-coherent) 16B load, NO waitcnt — caller must drain vmcnt before use.
__device__ inline uint4 ld_c16(const ushort_t* p) {
    uint4 d;
    asm volatile("global_load_dwordx4 %0, %1, off sc0 sc1" : "=v"(d) : "v"(p) : "memory");
    return d;
}
__device__ inline bf16x8 as_bf(uint4 v) { return __builtin_bit_cast(bf16x8, v); }
__device__ inline void st_a8(ushort_t* p, ull v) {
    __hip_atomic_store((ull*)p, v, __ATOMIC_RELAXED, __HIP_MEMORY_SCOPE_AGENT);
}
__device__ inline float sigm(float x) { return 1.f / (1.f + __expf(-x)); }

#define MFMA(a, b, c) __builtin_amdgcn_mfma_f32_16x16x32_bf16((a), (b), (c), 0, 0, 0)

__device__ inline void b_arrive(uint32* flags, uint32 val) {
    asm volatile("s_waitcnt vmcnt(0)" ::: "memory");
    __syncthreads();
    if (threadIdx.x == 0)
        __hip_atomic_store(flags + (uint32)blockIdx.x * 32, val,
                           __ATOMIC_RELAXED, __HIP_MEMORY_SCOPE_AGENT);
}
__device__ inline void b_wait(uint32* flags, uint32 val) {
    if (threadIdx.x < 64) {
        uint32 v;
        do {
            v = __hip_atomic_load(flags + threadIdx.x * 32,
                                  __ATOMIC_RELAXED, __HIP_MEMORY_SCOPE_AGENT);
        } while (__any((int)(v < val)));
    }
    __syncthreads();
    asm volatile("" ::: "memory");
}

__global__ __launch_bounds__(256) void k_init(const float* __restrict__ state,
                                              ushort_t* __restrict__ HB, uint32* flags) {
    int i = blockIdx.x * 256 + threadIdx.x;
    if (i < Bb * Hh) HB[i] = f2b(state[i]);
    if (i < 2112) flags[i] = 0;
}

__global__ __launch_bounds__(256) void k_xb(const float* __restrict__ inp,
                                            ushort_t* __restrict__ XB) {
    size_t i = ((size_t)blockIdx.x * 256 + threadIdx.x) * 8;
    bf16x8 v = ld_x8(inp + i);
    *reinterpret_cast<uint4*>(XB + i) = __builtin_bit_cast(uint4, v);
}

// WT[g][n][k] = bf16( k<512 ? Wx_g[k][n] : Wh_g[k-512][n] )
__global__ __launch_bounds__(256) void k_wt(const float* __restrict__ Wxz, const float* __restrict__ Whz,
                                            const float* __restrict__ Wxr, const float* __restrict__ Whr,
                                            const float* __restrict__ Wxh, const float* __restrict__ Whh,
                                            ushort_t* __restrict__ WT) {
    __shared__ float lds[64][65];
    int id = blockIdx.x;
    int g = id / 384, rem = id % 384, nt = rem / 24, kt = rem % 24;
    const float* Wx = (g == 0) ? Wxz : (g == 1) ? Wxr : Wxh;
    const float* Wh = (g == 0) ? Whz : (g == 1) ? Whr : Whh;
    int n0 = nt * 64, k0 = kt * 64;
    int tr = threadIdx.x >> 6, tc = threadIdx.x & 63;
    #pragma unroll
    for (int i = 0; i < 16; i++) {
        int kl = i * 4 + tr, k = k0 + kl;
        lds[kl][tc] = (k < 512) ? Wx[(size_t)k * Hh + n0 + tc]
                                : Wh[(size_t)(k - 512) * Hh + n0 + tc];
    }
    __syncthreads();
    #pragma unroll
    for (int i = 0; i < 16; i++) {
        int nl = i * 4 + tr;
        WT[((size_t)g * Hh + n0 + nl) * KK + k0 + tc] = f2b(lds[tc][nl]);
    }
}

// 8 waves: pair (w, w+4) owns m-tile w. z-wave (w<4): z-gate K=1536 + h-gate x-part;
// r-wave: r-gate K=1536. Phase B: K=1024 split halves across the pair.
__global__ __launch_bounds__(512, 2) void gru_persist(
    const float* __restrict__ inp, const ushort_t* __restrict__ XB, int use_xb,
    const float* __restrict__ bz, const float* __restrict__ br, const float* __restrict__ bh,
    ushort_t* HB, ushort_t* RH, const ushort_t* __restrict__ WT,
    uint32* flags, float* __restrict__ out) {
    __shared__ ushort_t WL[3 * 48 * 512];   // 147456 B, slot-XOR-swizzled 1KB tiles
    __shared__ float    XCH[4 * 256];       // 4096 B: rr (phase A) / B-partial (phase B)
    __shared__ ushort_t STG[4 * 256];       // 2048 B: z-wave store coalescing

    const int bi = blockIdx.x;
    const int tid = threadIdx.x;

    // ---- prologue: stage weights into swizzled LDS tiles ----
    for (int idx = tid; idx < 9216; idx += 512) {     // 3g x 16col x 192 16B-chunks
        int g = idx / 3072, r = idx % 3072, col = r / 192, c8 = r % 192;
        int kc = c8 >> 2, slot = c8 & 3, ps = slot ^ ((col >> 1) & 3);
        const ushort_t* src = WT + ((size_t)g * Hh + bi * 16 + col) * KK + c8 * 8;
        *reinterpret_cast<uint4*>(WL + g * 24576 + kc * 512 + col * 32 + ps * 8) =
            *reinterpret_cast<const uint4*>(src);
    }

    const int l = tid & 63, w = tid >> 6;
    const int m = w & 3;
    const bool isZ = (w < 4);
    const int lrow = l & 15, lq = l >> 4;
    const int ncol = bi * 16 + lrow;
    const int wloff = lrow * 32 + (lq ^ ((lrow >> 1) & 3)) * 8;

    #define WTILE(g, kc) ld_bf8(WL + (g) * 24576 + (kc) * 512 + wloff)

    const int arow = m * 16 + lrow;
    const float*    xF  = inp + (size_t)arow * (Tt * Dd) + lq * 8;
    const ushort_t* xBp = XB  + (size_t)arow * (Tt * Dd) + lq * 8;
    const ushort_t* hb  = HB  + arow * Hh + lq * 8;
    const ushort_t* rb  = RH  + arow * Hh + lq * 8 + (isZ ? 0 : 512);  // B-phase K-half
    const int gA = isZ ? 0 : 1;                                        // phase-A gate
    const int kB = isZ ? 16 : 32;                                      // B-phase tile base
    const float bzv = bz[ncol], brv = br[ncol], bhv = bh[ncol];
    const int xch_i = m * 256 + l * 4;

    // z-wave store path
    const size_t strow  = (size_t)(w * 16 + (l >> 2)) * Hh + bi * 16 + (l & 3) * 4;
    const int    stg_wr = (w & 3) * 256;
    const int    stg_rd = (w & 3) * 256 + (l >> 2) * 16 + (l & 3) * 4;

    float hold[4];
    if (isZ) {
        #pragma unroll
        for (int j = 0; j < 4; j++)
            hold[j] = b2f(HB[(size_t)(m * 16 + lq * 4 + j) * Hh + ncol]);
    }

    __syncthreads();

    for (int t = 0; t < Tt; ++t) {
        // ---- x fragments + x-part MFMAs (no HB dependence; overlaps barrier 2t) ----
        bf16x8 xa[16];
        if (use_xb) {
            #pragma unroll
            for (int i = 0; i < 16; i++) xa[i] = ld_bf8(xBp + (size_t)t * Dd + i * 32);
        } else {
            #pragma unroll
            for (int i = 0; i < 16; i++) xa[i] = ld_x8(xF + (size_t)t * Dd + i * 32);
        }
        const f32x4 z4 = {0.f, 0.f, 0.f, 0.f};
        f32x4 g0 = z4, g1 = z4;            // z: az, ahx ; r: ar, (unused)
        if (isZ) {
            #pragma unroll
            for (int kk = 0; kk < 16; kk++) {
                g0 = MFMA(xa[kk], WTILE(0, kk), g0);
                g1 = MFMA(xa[kk], WTILE(2, kk), g1);
            }
        } else {
            #pragma unroll
            for (int kk = 0; kk < 16; kk++)
                g0 = MFMA(xa[kk], WTILE(1, kk), g0);
        }

        b_wait(flags, 2u * (uint32)t);     // HB(t) visible

        // ---- phase A h-part: burst 32 coherent 16B loads, single drain, then MFMAs ----
        uint4 Ah[32];
        #pragma unroll
        for (int i = 0; i < 32; i++) Ah[i] = ld_c16(hb + i * 32);
        asm volatile("s_waitcnt vmcnt(0)" ::: "memory");
        __builtin_amdgcn_sched_barrier(0);
        #pragma unroll
        for (int kk = 0; kk < 32; kk++)
            g0 = MFMA(as_bf(Ah[kk]), WTILE(gA, 16 + kk), g0);

        if (!isZ) {                         // r-wave publishes r
            #pragma unroll
            for (int j = 0; j < 4; j++)
                XCH[m * 256 + (lq * 4 + j) * 16 + lrow] = sigm(g0[j] + brv);
        }
        __syncthreads();
        float zreg[4];
        if (isZ) {                          // z-wave: z, stage R*H, store
            #pragma unroll
            for (int j = 0; j < 4; j++) {
                zreg[j] = sigm(g0[j] + bzv);
                float rr = XCH[m * 256 + (lq * 4 + j) * 16 + lrow];
                STG[stg_wr + (lq * 4 + j) * 16 + lrow] = f2b(rr * hold[j]);
            }
            asm volatile("s_waitcnt lgkmcnt(0)" ::: "memory");
            st_a8(RH + strow, *reinterpret_cast<const ull*>(&STG[stg_rd]));
        }
        b_arrive(flags, 2u * (uint32)t + 1u);
        b_wait(flags, 2u * (uint32)t + 1u); // RH visible

        // ---- phase B: (R*H)@W_hh K-half per wave of the pair ----
        uint4 Ar[16];
        #pragma unroll
        for (int i = 0; i < 16; i++) Ar[i] = ld_c16(rb + i * 32);
        asm volatile("s_waitcnt vmcnt(0)" ::: "memory");
        __builtin_amdgcn_sched_barrier(0);
        f32x4 ha = z4, hbp = z4;
        #pragma unroll
        for (int kk = 0; kk < 16; kk += 2) {
            ha  = MFMA(as_bf(Ar[kk]),     WTILE(2, kB + kk),     ha);
            hbp = MFMA(as_bf(Ar[kk + 1]), WTILE(2, kB + kk + 1), hbp);
        }
        ha += hbp;
        if (!isZ) *reinterpret_cast<f32x4*>(&XCH[xch_i]) = ha;
        __syncthreads();
        if (isZ) {
            f32x4 tot = ha + g1 + *reinterpret_cast<const f32x4*>(&XCH[xch_i]);
            float hn[4];
            #pragma unroll
            for (int j = 0; j < 4; j++) {
                float pre = tot[j] + bhv;
                float e = __expf(-2.f * fabsf(pre));
                float th = (1.f - e) / (1.f + e);
                th = copysignf(th, pre);
                float v = zreg[j] * hold[j] + (1.f - zreg[j]) * th;
                hold[j] = v;
                hn[j] = v;
                STG[stg_wr + (lq * 4 + j) * 16 + lrow] = f2b(v);
            }
            asm volatile("s_waitcnt lgkmcnt(0)" ::: "memory");
            st_a8(HB + strow, *reinterpret_cast<const ull*>(&STG[stg_rd]));
            *reinterpret_cast<float4*>(out + (size_t)ncol * (Tt * Bb) + (size_t)t * Bb + m * 16 + lq * 4) =
                make_float4(hn[0], hn[1], hn[2], hn[3]);
            if (t == Tt - 1) {
                #pragma unroll
                for (int j = 0; j < 4; j++)
                    out[OUT2_OFF + (size_t)(m * 16 + lq * 4 + j) * Hh + ncol] = hn[j];
            }
        }
        b_arrive(flags, 2u * (uint32)t + 2u);
    }
    #undef WTILE
}

extern "C" void kernel_launch(void* const* d_in, const int* in_sizes, int n_in,
                              void* d_out, int out_size, void* d_ws, size_t ws_size,
                              hipStream_t stream) {
    const float* inp   = (const float*)d_in[0];
    const float* state = (const float*)d_in[1];
    const float* Wxz   = (const float*)d_in[2];
    const float* Whz   = (const float*)d_in[3];
    const float* bz    = (const float*)d_in[4];
    const float* Wxr   = (const float*)d_in[5];
    const float* Whr   = (const float*)d_in[6];
    const float* br    = (const float*)d_in[7];
    const float* Wxh   = (const float*)d_in[8];
    const float* Whh   = (const float*)d_in[9];
    const float* bh    = (const float*)d_in[10];
    float* out = (float*)d_out;

    char* ws = (char*)d_ws;
    ushort_t* HB    = (ushort_t*)(ws);
    ushort_t* RH    = (ushort_t*)(ws + 131072);
    ushort_t* WT    = (ushort_t*)(ws + 262144);
    uint32*   flags = (uint32*)(ws + FLAGS_OFF);
    ushort_t* XB    = (ushort_t*)(ws + XB_OFF);
    int use_xb = (ws_size >= XB_OFF + XB_BYTES) ? 1 : 0;

    k_init<<<dim3(256), dim3(256), 0, stream>>>(state, HB, flags);
    k_wt<<<dim3(1152), dim3(256), 0, stream>>>(Wxz, Whz, Wxr, Whr, Wxh, Whh, WT);
    if (use_xb)
        k_xb<<<dim3(8192), dim3(256), 0, stream>>>(inp, XB);

    void* args[] = {(void*)&inp, (void*)&XB, (void*)&use_xb,
                    (void*)&bz, (void*)&br, (void*)&bh,
                    (void*)&HB, (void*)&RH, (void*)&WT, (void*)&flags, (void*)&out};
    hipError_t e = hipLaunchCooperativeKernel((const void*)gru_persist, dim3(NBLK), dim3(512),
                                              args, 0, stream);
    if (e != hipSuccess) {
        gru_persist<<<dim3(NBLK), dim3(512), 0, stream>>>(inp, XB, use_xb, bz, br, bh,
                                                          HB, RH, WT, flags, out);
    }
}

// Round 7
// 8898.170 us; speedup vs baseline: 1.2363x; 1.1133x over previous
//
#include <hip/hip_runtime.h>
#include <hip/hip_bf16.h>

typedef unsigned short ushort_t;
typedef unsigned int uint32;
typedef unsigned long long ull;
typedef short bf16x8 __attribute__((ext_vector_type(8)));
typedef float f32x4 __attribute__((ext_vector_type(4)));

#define Bb 64
#define Tt 512
#define Dd 512
#define Hh 1024
#define KK 1536
#define NBLK 64
#define OUT2_OFF 33554432ull
#define FLAGS_OFF 9699328ull
#define XB_OFF    9707776ull
#define XB_BYTES  33554432ull

// ws: HB @0 (128K) | RH @131072 (128K) | WT @262144 (9.4M) | flags @9699328 | XB @9707776 (32M opt)

__device__ inline ushort_t f2b(float f) {
    __hip_bfloat16 h = __float2bfloat16(f);
    return __builtin_bit_cast(ushort_t, h);
}
__device__ inline float b2f(ushort_t u) {
    uint32 x = ((uint32)u) << 16;
    return __builtin_bit_cast(float, x);
}
__device__ inline bf16x8 ld_bf8(const ushort_t* p) {
    uint4 v = *reinterpret_cast<const uint4*>(p);
    return __builtin_bit_cast(bf16x8, v);
}
__device__ inline bf16x8 ld_x8(const float* p) {
    float4 u = *reinterpret_cast<const float4*>(p);
    float4 v = *reinterpret_cast<const float4*>(p + 4);
    bf16x8 a;
    a[0] = (short)f2b(u.x); a[1] = (short)f2b(u.y); a[2] = (short)f2b(u.z); a[3] = (short)f2b(u.w);
    a[4] = (short)f2b(v.x); a[5] = (short)f2b(v.y); a[6] = (short)f2b(v.z); a[7] = (short)f2b(v.w);
    return a;
}
// LLC-coherent 16B load (bypass L1/L2); caller drains vmcnt before use.
__device__ inline uint4 ld_c16(const ushort_t* p) {
    uint4 d;
    asm volatile("global_load_dwordx4 %0, %1, off sc0 sc1" : "=v"(d) : "v"(p) : "memory");
    return d;
}
__device__ inline bf16x8 as_bf(uint4 v) { return __builtin_bit_cast(bf16x8, v); }
__device__ inline void st_a8(ushort_t* p, ull v) {
    __hip_atomic_store((ull*)p, v, __ATOMIC_RELAXED, __HIP_MEMORY_SCOPE_AGENT);
}
__device__ inline uint32 ld_flag(const uint32* p) {
    return __hip_atomic_load(p, __ATOMIC_RELAXED, __HIP_MEMORY_SCOPE_AGENT);
}
__device__ inline float sigm(float x) { return 1.f / (1.f + __expf(-x)); }

#define MFMA(a, b, c) __builtin_amdgcn_mfma_f32_16x16x32_bf16((a), (b), (c), 0, 0, 0)

__global__ __launch_bounds__(256) void k_init(const float* __restrict__ state,
                                              ushort_t* __restrict__ HB, uint32* flags) {
    int i = blockIdx.x * 256 + threadIdx.x;
    if (i < Bb * Hh) HB[i] = f2b(state[i]);
    if (i < 2112) flags[i] = 0;
}

__global__ __launch_bounds__(256) void k_xb(const float* __restrict__ inp,
                                            ushort_t* __restrict__ XB) {
    size_t i = ((size_t)blockIdx.x * 256 + threadIdx.x) * 8;
    bf16x8 v = ld_x8(inp + i);
    *reinterpret_cast<uint4*>(XB + i) = __builtin_bit_cast(uint4, v);
}

// WT[g][n][k] = bf16( k<512 ? Wx_g[k][n] : Wh_g[k-512][n] )
__global__ __launch_bounds__(256) void k_wt(const float* __restrict__ Wxz, const float* __restrict__ Whz,
                                            const float* __restrict__ Wxr, const float* __restrict__ Whr,
                                            const float* __restrict__ Wxh, const float* __restrict__ Whh,
                                            ushort_t* __restrict__ WT) {
    __shared__ float lds[64][65];
    int id = blockIdx.x;
    int g = id / 384, rem = id % 384, nt = rem / 24, kt = rem % 24;
    const float* Wx = (g == 0) ? Wxz : (g == 1) ? Wxr : Wxh;
    const float* Wh = (g == 0) ? Whz : (g == 1) ? Whr : Whh;
    int n0 = nt * 64, k0 = kt * 64;
    int tr = threadIdx.x >> 6, tc = threadIdx.x & 63;
    #pragma unroll
    for (int i = 0; i < 16; i++) {
        int kl = i * 4 + tr, k = k0 + kl;
        lds[kl][tc] = (k < 512) ? Wx[(size_t)k * Hh + n0 + tc]
                                : Wh[(size_t)(k - 512) * Hh + n0 + tc];
    }
    __syncthreads();
    #pragma unroll
    for (int i = 0; i < 16; i++) {
        int nl = i * 4 + tr;
        WT[((size_t)g * Hh + n0 + nl) * KK + k0 + tc] = f2b(lds[tc][nl]);
    }
}

// 4 waves; wave w owns m-tile w (batch rows w*16..+16), block owns cols bi*16..+16.
__global__ __launch_bounds__(256, 1) void gru_persist(
    const float* __restrict__ inp, const ushort_t* __restrict__ XB, int use_xb,
    const float* __restrict__ bz, const float* __restrict__ br, const float* __restrict__ bh,
    ushort_t* HB, ushort_t* RH, const ushort_t* __restrict__ WT,
    uint32* flags, float* __restrict__ out) {
    __shared__ ushort_t WL[3 * 48 * 512];   // 147456 B, slot-XOR-swizzled 1KB tiles
    __shared__ ushort_t STG[4 * 256];       // per-wave 16x16 store-coalescing tile

    const int bi = blockIdx.x;
    const int tid = threadIdx.x;

    // ---- prologue: stage weights into swizzled LDS tiles ----
    for (int idx = tid; idx < 9216; idx += 256) {     // 3g x 16col x 192 16B-chunks
        int g = idx / 3072, r = idx % 3072, col = r / 192, c8 = r % 192;
        int kc = c8 >> 2, slot = c8 & 3, ps = slot ^ ((col >> 1) & 3);
        const ushort_t* src = WT + ((size_t)g * Hh + bi * 16 + col) * KK + c8 * 8;
        *reinterpret_cast<uint4*>(WL + g * 24576 + kc * 512 + col * 32 + ps * 8) =
            *reinterpret_cast<const uint4*>(src);
    }

    const int l = tid & 63, w = tid >> 6;
    const int lrow = l & 15, lq = l >> 4;
    const int ncol = bi * 16 + lrow;
    const int wloff = lrow * 32 + (lq ^ ((lrow >> 1) & 3)) * 8;
    const int c0 = bi & 3;                  // chunk stagger

    #define WTILE(g, kc) ld_bf8(WL + (g) * 24576 + (kc) * 512 + wloff)

    const int arow = w * 16 + lrow;
    const float*    xF = inp + (size_t)arow * (Tt * Dd) + lq * 8;
    const ushort_t* xBp = XB + (size_t)arow * (Tt * Dd) + lq * 8;
    const ushort_t* hb = HB + arow * Hh + lq * 8;
    const ushort_t* rb = RH + arow * Hh + lq * 8;
    const float bzv = bz[ncol], brv = br[ncol], bhv = bh[ncol];

    const size_t strow  = (size_t)(w * 16 + (l >> 2)) * Hh + bi * 16 + (l & 3) * 4;
    const int    stg_wr = w * 256;
    const int    stg_rd = w * 256 + (l >> 2) * 16 + (l & 3) * 4;

    float hold[4];
    #pragma unroll
    for (int j = 0; j < 4; j++)
        hold[j] = b2f(HB[(size_t)(w * 16 + lq * 4 + j) * Hh + ncol]);

    __syncthreads();

    const f32x4 z4 = {0.f, 0.f, 0.f, 0.f};
    f32x4 az = z4, ar = z4, ahx = z4;

    // x fragments + x-part MFMAs for t=0
    bf16x8 xa[16];
    if (use_xb) {
        #pragma unroll
        for (int i = 0; i < 16; i++) xa[i] = ld_bf8(xBp + i * 32);
    } else {
        #pragma unroll
        for (int i = 0; i < 16; i++) xa[i] = ld_x8(xF + i * 32);
    }
    #pragma unroll
    for (int kk = 0; kk < 16; kk++) {
        az  = MFMA(xa[kk], WTILE(0, kk), az);
        ar  = MFMA(xa[kk], WTILE(1, kk), ar);
        ahx = MFMA(xa[kk], WTILE(2, kk), ahx);
    }

    for (int t = 0; t < Tt; ++t) {
        const uint32 valH = 2u * (uint32)t;        // H(t) ready
        const uint32 valR = 2u * (uint32)t + 1u;   // RH(t) ready

        // ================= PHASE A: consume H(t) -> az, ar =================
        {
            uint32 v = ld_flag(flags + l * 32);
            if (__all((int)(v >= valH))) {
                uint4 A[32];
                #pragma unroll
                for (int i = 0; i < 32; i++) A[i] = ld_c16(hb + i * 32);
                asm volatile("s_waitcnt vmcnt(0)" ::: "memory");
                __builtin_amdgcn_sched_barrier(0);
                #pragma unroll
                for (int kk = 0; kk < 32; kk++) {
                    az = MFMA(as_bf(A[kk]), WTILE(0, 16 + kk), az);
                    ar = MFMA(as_bf(A[kk]), WTILE(1, 16 + kk), ar);
                }
            } else {
                for (int ci = 0; ci < 4; ci++) {
                    int c = (c0 + ci) & 3;
                    uint32 vv;
                    do { vv = ld_flag(flags + (c * 16 + (l & 15)) * 32); }
                    while (__any((int)(vv < valH)));
                    uint4 A[8];
                    #pragma unroll
                    for (int i = 0; i < 8; i++) A[i] = ld_c16(hb + (c * 8 + i) * 32);
                    asm volatile("s_waitcnt vmcnt(0)" ::: "memory");
                    __builtin_amdgcn_sched_barrier(0);
                    #pragma unroll
                    for (int i = 0; i < 8; i++) {
                        int kk = c * 8 + i;
                        az = MFMA(as_bf(A[i]), WTILE(0, 16 + kk), az);
                        ar = MFMA(as_bf(A[i]), WTILE(1, 16 + kk), ar);
                    }
                }
            }
        }
        // finalize z, r; stage + store RH slice
        float zreg[4];
        #pragma unroll
        for (int j = 0; j < 4; j++) {
            zreg[j] = sigm(az[j] + bzv);
            float rr = sigm(ar[j] + brv);
            STG[stg_wr + (lq * 4 + j) * 16 + lrow] = f2b(rr * hold[j]);
        }
        asm volatile("s_waitcnt lgkmcnt(0)" ::: "memory");
        st_a8(RH + strow, *reinterpret_cast<const ull*>(&STG[stg_rd]));
        asm volatile("s_waitcnt vmcnt(0)" ::: "memory");
        __syncthreads();
        if (tid == 0)
            __hip_atomic_store(flags + (uint32)bi * 32, valR,
                               __ATOMIC_RELAXED, __HIP_MEMORY_SCOPE_AGENT);

        // cover RH propagation: issue x(t+1) fragment loads
        if (t < Tt - 1) {
            if (use_xb) {
                #pragma unroll
                for (int i = 0; i < 16; i++) xa[i] = ld_bf8(xBp + (size_t)(t + 1) * Dd + i * 32);
            } else {
                #pragma unroll
                for (int i = 0; i < 16; i++) xa[i] = ld_x8(xF + (size_t)(t + 1) * Dd + i * 32);
            }
        }

        // ================= PHASE B: consume RH(t) -> ah =================
        f32x4 ah0 = ahx, ah1 = z4;
        {
            uint32 v = ld_flag(flags + l * 32);
            if (__all((int)(v >= valR))) {
                uint4 A[32];
                #pragma unroll
                for (int i = 0; i < 32; i++) A[i] = ld_c16(rb + i * 32);
                asm volatile("s_waitcnt vmcnt(0)" ::: "memory");
                __builtin_amdgcn_sched_barrier(0);
                #pragma unroll
                for (int kk = 0; kk < 32; kk += 2) {
                    ah0 = MFMA(as_bf(A[kk]),     WTILE(2, 16 + kk),     ah0);
                    ah1 = MFMA(as_bf(A[kk + 1]), WTILE(2, 16 + kk + 1), ah1);
                }
            } else {
                for (int ci = 0; ci < 4; ci++) {
                    int c = (c0 + ci) & 3;
                    uint32 vv;
                    do { vv = ld_flag(flags + (c * 16 + (l & 15)) * 32); }
                    while (__any((int)(vv < valR)));
                    uint4 A[8];
                    #pragma unroll
                    for (int i = 0; i < 8; i++) A[i] = ld_c16(rb + (c * 8 + i) * 32);
                    asm volatile("s_waitcnt vmcnt(0)" ::: "memory");
                    __builtin_amdgcn_sched_barrier(0);
                    #pragma unroll
                    for (int i = 0; i < 8; i++) {
                        int kk = c * 8 + i;
                        if (i & 1) ah1 = MFMA(as_bf(A[i]), WTILE(2, 16 + kk), ah1);
                        else       ah0 = MFMA(as_bf(A[i]), WTILE(2, 16 + kk), ah0);
                    }
                }
            }
        }
        f32x4 aht = ah0 + ah1;
        float hn[4];
        #pragma unroll
        for (int j = 0; j < 4; j++) {
            float pre = aht[j] + bhv;
            float e = __expf(-2.f * fabsf(pre));
            float th = (1.f - e) / (1.f + e);
            th = copysignf(th, pre);
            float v = zreg[j] * hold[j] + (1.f - zreg[j]) * th;
            hold[j] = v;
            hn[j] = v;
            STG[stg_wr + (lq * 4 + j) * 16 + lrow] = f2b(v);
        }
        asm volatile("s_waitcnt lgkmcnt(0)" ::: "memory");
        st_a8(HB + strow, *reinterpret_cast<const ull*>(&STG[stg_rd]));
        asm volatile("s_waitcnt vmcnt(0)" ::: "memory");
        __syncthreads();
        if (tid == 0)
            __hip_atomic_store(flags + (uint32)bi * 32, valR + 1u,
                               __ATOMIC_RELAXED, __HIP_MEMORY_SCOPE_AGENT);

        // after the flag: out stores (consumed by nobody in-kernel)
        *reinterpret_cast<float4*>(out + (size_t)ncol * (Tt * Bb) + (size_t)t * Bb + w * 16 + lq * 4) =
            make_float4(hn[0], hn[1], hn[2], hn[3]);
        if (t == Tt - 1) {
            #pragma unroll
            for (int j = 0; j < 4; j++)
                out[OUT2_OFF + (size_t)(w * 16 + lq * 4 + j) * Hh + ncol] = hn[j];
        }

        // cover H(t+1) propagation: x(t+1) MFMAs
        az = z4; ar = z4; ahx = z4;
        if (t < Tt - 1) {
            #pragma unroll
            for (int kk = 0; kk < 16; kk++) {
                az  = MFMA(xa[kk], WTILE(0, kk), az);
                ar  = MFMA(xa[kk], WTILE(1, kk), ar);
                ahx = MFMA(xa[kk], WTILE(2, kk), ahx);
            }
        }
    }
    #undef WTILE
}

extern "C" void kernel_launch(void* const* d_in, const int* in_sizes, int n_in,
                              void* d_out, int out_size, void* d_ws, size_t ws_size,
                              hipStream_t stream) {
    const float* inp   = (const float*)d_in[0];
    const float* state = (const float*)d_in[1];
    const float* Wxz   = (const float*)d_in[2];
    const float* Whz   = (const float*)d_in[3];
    const float* bz    = (const float*)d_in[4];
    const float* Wxr   = (const float*)d_in[5];
    const float* Whr   = (const float*)d_in[6];
    const float* br    = (const float*)d_in[7];
    const float* Wxh   = (const float*)d_in[8];
    const float* Whh   = (const float*)d_in[9];
    const float* bh    = (const float*)d_in[10];
    float* out = (float*)d_out;

    char* ws = (char*)d_ws;
    ushort_t* HB    = (ushort_t*)(ws);
    ushort_t* RH    = (ushort_t*)(ws + 131072);
    ushort_t* WT    = (ushort_t*)(ws + 262144);
    uint32*   flags = (uint32*)(ws + FLAGS_OFF);
    ushort_t* XB    = (ushort_t*)(ws + XB_OFF);
    int use_xb = (ws_size >= XB_OFF + XB_BYTES) ? 1 : 0;

    k_init<<<dim3(256), dim3(256), 0, stream>>>(state, HB, flags);
    k_wt<<<dim3(1152), dim3(256), 0, stream>>>(Wxz, Whz, Wxr, Whr, Wxh, Whh, WT);
    if (use_xb)
        k_xb<<<dim3(8192), dim3(256), 0, stream>>>(inp, XB);

    void* args[] = {(void*)&inp, (void*)&XB, (void*)&use_xb,
                    (void*)&bz, (void*)&br, (void*)&bh,
                    (void*)&HB, (void*)&RH, (void*)&WT, (void*)&flags, (void*)&out};
    hipError_t e = hipLaunchCooperativeKernel((const void*)gru_persist, dim3(NBLK), dim3(256),
                                              args, 0, stream);
    if (e != hipSuccess) {
        gru_persist<<<dim3(NBLK), dim3(256), 0, stream>>>(inp, XB, use_xb, bz, br, bh,
                                                          HB, RH, WT, flags, out);
    }
}

// Round 8
// 8664.266 us; speedup vs baseline: 1.2697x; 1.0270x over previous
//
#include <hip/hip_runtime.h>
#include <hip/hip_bf16.h>

typedef unsigned short ushort_t;
typedef unsigned int uint32;
typedef unsigned long long ull;
typedef short bf16x8 __attribute__((ext_vector_type(8)));
typedef float f32x4 __attribute__((ext_vector_type(4)));

#define Bb 64
#define Tt 512
#define Dd 512
#define Hh 1024
#define KK 1536
#define NBLK 64
#define OUT2_OFF 33554432ull
#define FLAGS_OFF 9699328ull
#define XB_OFF    9707776ull
#define XB_BYTES  33554432ull

// ws: HB @0 (128K) | RH @131072 (128K) | WT @262144 (9.4M) | flags @9699328 | XB @9707776 (32M opt)

__device__ inline ushort_t f2b(float f) {
    __hip_bfloat16 h = __float2bfloat16(f);
    return __builtin_bit_cast(ushort_t, h);
}
__device__ inline float b2f(ushort_t u) {
    uint32 x = ((uint32)u) << 16;
    return __builtin_bit_cast(float, x);
}
__device__ inline bf16x8 ld_bf8(const ushort_t* p) {
    uint4 v = *reinterpret_cast<const uint4*>(p);
    return __builtin_bit_cast(bf16x8, v);
}
__device__ inline bf16x8 ld_x8(const float* p) {
    float4 u = *reinterpret_cast<const float4*>(p);
    float4 v = *reinterpret_cast<const float4*>(p + 4);
    bf16x8 a;
    a[0] = (short)f2b(u.x); a[1] = (short)f2b(u.y); a[2] = (short)f2b(u.z); a[3] = (short)f2b(u.w);
    a[4] = (short)f2b(v.x); a[5] = (short)f2b(v.y); a[6] = (short)f2b(v.z); a[7] = (short)f2b(v.w);
    return a;
}
// LLC-coherent 16B load (bypass L1/L2); caller drains vmcnt before use.
__device__ inline uint4 ld_c16(const ushort_t* p) {
    uint4 d;
    asm volatile("global_load_dwordx4 %0, %1, off sc0 sc1" : "=v"(d) : "v"(p) : "memory");
    return d;
}
__device__ inline bf16x8 as_bf(uint4 v) { return __builtin_bit_cast(bf16x8, v); }
__device__ inline void st_a8(ushort_t* p, ull v) {
    __hip_atomic_store((ull*)p, v, __ATOMIC_RELAXED, __HIP_MEMORY_SCOPE_AGENT);
}
__device__ inline uint32 ld_flag(const uint32* p) {
    return __hip_atomic_load(p, __ATOMIC_RELAXED, __HIP_MEMORY_SCOPE_AGENT);
}
__device__ inline float sigm(float x) { return 1.f / (1.f + __expf(-x)); }

#define MFMA(a, b, c) __builtin_amdgcn_mfma_f32_16x16x32_bf16((a), (b), (c), 0, 0, 0)

__global__ __launch_bounds__(256) void k_init(const float* __restrict__ state,
                                              ushort_t* __restrict__ HB, uint32* flags) {
    int i = blockIdx.x * 256 + threadIdx.x;
    if (i < Bb * Hh) HB[i] = f2b(state[i]);
    if (i < 2112) flags[i] = 0;
}

__global__ __launch_bounds__(256) void k_xb(const float* __restrict__ inp,
                                            ushort_t* __restrict__ XB) {
    size_t i = ((size_t)blockIdx.x * 256 + threadIdx.x) * 8;
    bf16x8 v = ld_x8(inp + i);
    *reinterpret_cast<uint4*>(XB + i) = __builtin_bit_cast(uint4, v);
}

// WT[g][n][k] = bf16( k<512 ? Wx_g[k][n] : Wh_g[k-512][n] )
__global__ __launch_bounds__(256) void k_wt(const float* __restrict__ Wxz, const float* __restrict__ Whz,
                                            const float* __restrict__ Wxr, const float* __restrict__ Whr,
                                            const float* __restrict__ Wxh, const float* __restrict__ Whh,
                                            ushort_t* __restrict__ WT) {
    __shared__ float lds[64][65];
    int id = blockIdx.x;
    int g = id / 384, rem = id % 384, nt = rem / 24, kt = rem % 24;
    const float* Wx = (g == 0) ? Wxz : (g == 1) ? Wxr : Wxh;
    const float* Wh = (g == 0) ? Whz : (g == 1) ? Whr : Whh;
    int n0 = nt * 64, k0 = kt * 64;
    int tr = threadIdx.x >> 6, tc = threadIdx.x & 63;
    #pragma unroll
    for (int i = 0; i < 16; i++) {
        int kl = i * 4 + tr, k = k0 + kl;
        lds[kl][tc] = (k < 512) ? Wx[(size_t)k * Hh + n0 + tc]
                                : Wh[(size_t)(k - 512) * Hh + n0 + tc];
    }
    __syncthreads();
    #pragma unroll
    for (int i = 0; i < 16; i++) {
        int nl = i * 4 + tr;
        WT[((size_t)g * Hh + n0 + nl) * KK + k0 + tc] = f2b(lds[tc][nl]);
    }
}

// 4 waves; wave w owns m-tile w (batch rows w*16..+16), block owns cols bi*16..+16.
__global__ __launch_bounds__(256, 1) void gru_persist(
    const float* __restrict__ inp, const ushort_t* __restrict__ XB, int use_xb,
    const float* __restrict__ bz, const float* __restrict__ br, const float* __restrict__ bh,
    ushort_t* HB, ushort_t* RH, const ushort_t* __restrict__ WT,
    uint32* flags, float* __restrict__ out) {
    __shared__ ushort_t WL[3 * 48 * 512];   // 147456 B, slot-XOR-swizzled 1KB tiles
    __shared__ ushort_t STG[4 * 256];       // per-wave 16x16 store-coalescing tile

    const int bi = blockIdx.x;
    const int tid = threadIdx.x;

    // ---- prologue: stage weights into swizzled LDS tiles ----
    for (int idx = tid; idx < 9216; idx += 256) {     // 3g x 16col x 192 16B-chunks
        int g = idx / 3072, r = idx % 3072, col = r / 192, c8 = r % 192;
        int kc = c8 >> 2, slot = c8 & 3, ps = slot ^ ((col >> 1) & 3);
        const ushort_t* src = WT + ((size_t)g * Hh + bi * 16 + col) * KK + c8 * 8;
        *reinterpret_cast<uint4*>(WL + g * 24576 + kc * 512 + col * 32 + ps * 8) =
            *reinterpret_cast<const uint4*>(src);
    }

    const int l = tid & 63, w = tid >> 6;
    const int lrow = l & 15, lq = l >> 4;
    const int ncol = bi * 16 + lrow;
    const int wloff = lrow * 32 + (lq ^ ((lrow >> 1) & 3)) * 8;
    const int c0 = (bi + w) & 3;            // chunk stagger: per block AND per wave

    #define WTILE(g, kc) ld_bf8(WL + (g) * 24576 + (kc) * 512 + wloff)

    const int arow = w * 16 + lrow;
    const float*    xF = inp + (size_t)arow * (Tt * Dd) + lq * 8;
    const ushort_t* xBp = XB + (size_t)arow * (Tt * Dd) + lq * 8;
    const ushort_t* hb = HB + arow * Hh + lq * 8;
    const ushort_t* rb = RH + arow * Hh + lq * 8;
    const float bzv = bz[ncol], brv = br[ncol], bhv = bh[ncol];

    const size_t strow  = (size_t)(w * 16 + (l >> 2)) * Hh + bi * 16 + (l & 3) * 4;
    const int    stg_wr = w * 256;
    const int    stg_rd = w * 256 + (l >> 2) * 16 + (l & 3) * 4;

    float hold[4];
    #pragma unroll
    for (int j = 0; j < 4; j++)
        hold[j] = b2f(HB[(size_t)(w * 16 + lq * 4 + j) * Hh + ncol]);

    __syncthreads();

    const f32x4 z4 = {0.f, 0.f, 0.f, 0.f};
    f32x4 az = z4, ar = z4, ahx = z4;

    // x fragments + x-part MFMAs for t=0
    bf16x8 xa[16];
    if (use_xb) {
        #pragma unroll
        for (int i = 0; i < 16; i++) xa[i] = ld_bf8(xBp + i * 32);
    } else {
        #pragma unroll
        for (int i = 0; i < 16; i++) xa[i] = ld_x8(xF + i * 32);
    }
    #pragma unroll
    for (int kk = 0; kk < 16; kk++) {
        az  = MFMA(xa[kk], WTILE(0, kk), az);
        ar  = MFMA(xa[kk], WTILE(1, kk), ar);
        ahx = MFMA(xa[kk], WTILE(2, kk), ahx);
    }

    for (int t = 0; t < Tt; ++t) {
        const uint32 valH = 2u * (uint32)t;        // H(t) ready
        const uint32 valR = 2u * (uint32)t + 1u;   // RH(t) ready

        // ================= PHASE A: consume H(t) -> az, ar =================
        {
            uint32 v = ld_flag(flags + l * 32);    // one-shot fast check (not a loop)
            if (__all((int)(v >= valH))) {
                uint4 A[32];
                #pragma unroll
                for (int i = 0; i < 32; i++) A[i] = ld_c16(hb + i * 32);
                asm volatile("s_waitcnt vmcnt(0)" ::: "memory");
                __builtin_amdgcn_sched_barrier(0);
                #pragma unroll
                for (int kk = 0; kk < 32; kk++) {
                    az = MFMA(as_bf(A[kk]), WTILE(0, 16 + kk), az);
                    ar = MFMA(as_bf(A[kk]), WTILE(1, 16 + kk), ar);
                }
            } else {
                for (int ci = 0; ci < 4; ci++) {
                    int c = (c0 + ci) & 3;
                    // backoff poll: first check free, then sleep(1) (~64cy) between polls
                    uint32 vv = ld_flag(flags + (c * 16 + (l & 15)) * 32);
                    while (__any((int)(vv < valH))) {
                        __builtin_amdgcn_s_sleep(1);
                        vv = ld_flag(flags + (c * 16 + (l & 15)) * 32);
                    }
                    uint4 A[8];
                    #pragma unroll
                    for (int i = 0; i < 8; i++) A[i] = ld_c16(hb + (c * 8 + i) * 32);
                    asm volatile("s_waitcnt vmcnt(0)" ::: "memory");
                    __builtin_amdgcn_sched_barrier(0);
                    #pragma unroll
                    for (int i = 0; i < 8; i++) {
                        int kk = c * 8 + i;
                        az = MFMA(as_bf(A[i]), WTILE(0, 16 + kk), az);
                        ar = MFMA(as_bf(A[i]), WTILE(1, 16 + kk), ar);
                    }
                }
            }
        }
        // finalize z, r; stage + store RH slice
        float zreg[4];
        #pragma unroll
        for (int j = 0; j < 4; j++) {
            zreg[j] = sigm(az[j] + bzv);
            float rr = sigm(ar[j] + brv);
            STG[stg_wr + (lq * 4 + j) * 16 + lrow] = f2b(rr * hold[j]);
        }
        asm volatile("s_waitcnt lgkmcnt(0)" ::: "memory");
        st_a8(RH + strow, *reinterpret_cast<const ull*>(&STG[stg_rd]));
        asm volatile("s_waitcnt vmcnt(0)" ::: "memory");
        __syncthreads();
        if (tid == 0)
            __hip_atomic_store(flags + (uint32)bi * 32, valR,
                               __ATOMIC_RELAXED, __HIP_MEMORY_SCOPE_AGENT);

        // cover RH propagation: issue x(t+1) fragment loads
        if (t < Tt - 1) {
            if (use_xb) {
                #pragma unroll
                for (int i = 0; i < 16; i++) xa[i] = ld_bf8(xBp + (size_t)(t + 1) * Dd + i * 32);
            } else {
                #pragma unroll
                for (int i = 0; i < 16; i++) xa[i] = ld_x8(xF + (size_t)(t + 1) * Dd + i * 32);
            }
        }

        // ================= PHASE B: consume RH(t) -> ah =================
        f32x4 ah0 = ahx, ah1 = z4;
        {
            uint32 v = ld_flag(flags + l * 32);
            if (__all((int)(v >= valR))) {
                uint4 A[32];
                #pragma unroll
                for (int i = 0; i < 32; i++) A[i] = ld_c16(rb + i * 32);
                asm volatile("s_waitcnt vmcnt(0)" ::: "memory");
                __builtin_amdgcn_sched_barrier(0);
                #pragma unroll
                for (int kk = 0; kk < 32; kk += 2) {
                    ah0 = MFMA(as_bf(A[kk]),     WTILE(2, 16 + kk),     ah0);
                    ah1 = MFMA(as_bf(A[kk + 1]), WTILE(2, 16 + kk + 1), ah1);
                }
            } else {
                for (int ci = 0; ci < 4; ci++) {
                    int c = (c0 + ci) & 3;
                    uint32 vv = ld_flag(flags + (c * 16 + (l & 15)) * 32);
                    while (__any((int)(vv < valR))) {
                        __builtin_amdgcn_s_sleep(1);
                        vv = ld_flag(flags + (c * 16 + (l & 15)) * 32);
                    }
                    uint4 A[8];
                    #pragma unroll
                    for (int i = 0; i < 8; i++) A[i] = ld_c16(rb + (c * 8 + i) * 32);
                    asm volatile("s_waitcnt vmcnt(0)" ::: "memory");
                    __builtin_amdgcn_sched_barrier(0);
                    #pragma unroll
                    for (int i = 0; i < 8; i++) {
                        int kk = c * 8 + i;
                        if (i & 1) ah1 = MFMA(as_bf(A[i]), WTILE(2, 16 + kk), ah1);
                        else       ah0 = MFMA(as_bf(A[i]), WTILE(2, 16 + kk), ah0);
                    }
                }
            }
        }
        f32x4 aht = ah0 + ah1;
        float hn[4];
        #pragma unroll
        for (int j = 0; j < 4; j++) {
            float pre = aht[j] + bhv;
            float e = __expf(-2.f * fabsf(pre));
            float th = (1.f - e) / (1.f + e);
            th = copysignf(th, pre);
            float v = zreg[j] * hold[j] + (1.f - zreg[j]) * th;
            hold[j] = v;
            hn[j] = v;
            STG[stg_wr + (lq * 4 + j) * 16 + lrow] = f2b(v);
        }
        asm volatile("s_waitcnt lgkmcnt(0)" ::: "memory");
        st_a8(HB + strow, *reinterpret_cast<const ull*>(&STG[stg_rd]));
        asm volatile("s_waitcnt vmcnt(0)" ::: "memory");
        __syncthreads();
        if (tid == 0)
            __hip_atomic_store(flags + (uint32)bi * 32, valR + 1u,
                               __ATOMIC_RELAXED, __HIP_MEMORY_SCOPE_AGENT);

        // after the flag: out stores (consumed by nobody in-kernel)
        *reinterpret_cast<float4*>(out + (size_t)ncol * (Tt * Bb) + (size_t)t * Bb + w * 16 + lq * 4) =
            make_float4(hn[0], hn[1], hn[2], hn[3]);
        if (t == Tt - 1) {
            #pragma unroll
            for (int j = 0; j < 4; j++)
                out[OUT2_OFF + (size_t)(w * 16 + lq * 4 + j) * Hh + ncol] = hn[j];
        }

        // cover H(t+1) propagation: x(t+1) MFMAs
        az = z4; ar = z4; ahx = z4;
        if (t < Tt - 1) {
            #pragma unroll
            for (int kk = 0; kk < 16; kk++) {
                az  = MFMA(xa[kk], WTILE(0, kk), az);
                ar  = MFMA(xa[kk], WTILE(1, kk), ar);
                ahx = MFMA(xa[kk], WTILE(2, kk), ahx);
            }
        }
    }
    #undef WTILE
}

extern "C" void kernel_launch(void* const* d_in, const int* in_sizes, int n_in,
                              void* d_out, int out_size, void* d_ws, size_t ws_size,
                              hipStream_t stream) {
    const float* inp   = (const float*)d_in[0];
    const float* state = (const float*)d_in[1];
    const float* Wxz   = (const float*)d_in[2];
    const float* Whz   = (const float*)d_in[3];
    const float* bz    = (const float*)d_in[4];
    const float* Wxr   = (const float*)d_in[5];
    const float* Whr   = (const float*)d_in[6];
    const float* br    = (const float*)d_in[7];
    const float* Wxh   = (const float*)d_in[8];
    const float* Whh   = (const float*)d_in[9];
    const float* bh    = (const float*)d_in[10];
    float* out = (float*)d_out;

    char* ws = (char*)d_ws;
    ushort_t* HB    = (ushort_t*)(ws);
    ushort_t* RH    = (ushort_t*)(ws + 131072);
    ushort_t* WT    = (ushort_t*)(ws + 262144);
    uint32*   flags = (uint32*)(ws + FLAGS_OFF);
    ushort_t* XB    = (ushort_t*)(ws + XB_OFF);
    int use_xb = (ws_size >= XB_OFF + XB_BYTES) ? 1 : 0;

    k_init<<<dim3(256), dim3(256), 0, stream>>>(state, HB, flags);
    k_wt<<<dim3(1152), dim3(256), 0, stream>>>(Wxz, Whz, Wxr, Whr, Wxh, Whh, WT);
    if (use_xb)
        k_xb<<<dim3(8192), dim3(256), 0, stream>>>(inp, XB);

    void* args[] = {(void*)&inp, (void*)&XB, (void*)&use_xb,
                    (void*)&bz, (void*)&br, (void*)&bh,
                    (void*)&HB, (void*)&RH, (void*)&WT, (void*)&flags, (void*)&out};
    hipError_t e = hipLaunchCooperativeKernel((const void*)gru_persist, dim3(NBLK), dim3(256),
                                              args, 0, stream);
    if (e != hipSuccess) {
        gru_persist<<<dim3(NBLK), dim3(256), 0, stream>>>(inp, XB, use_xb, bz, br, bh,
                                                          HB, RH, WT, flags, out);
    }
}